// Round 3
// baseline (165.169 us; speedup 1.0000x reference)
//
#include <hip/hip_runtime.h>

#define GAT_H 12
#define GAT_N 4096
#define GAT_F 64
#define TJ    256
#define NTILE (GAT_N / TJ)
#define LOG2E 1.4426950408889634f
#define TAB_OFF 1024   // float offset of table within d_ws (4 KB)

// Prep: blocks 0..11 compute s_h = <W_h, a_src_h>, d_h = <W_h, a_dst_h>.
// Block 12 computes mean(x) (fallback for neighborless rows -> uniform attn).
__global__ __launch_bounds__(64) void gat_prep(const float* __restrict__ W,
                                               const float* __restrict__ a,
                                               const float* __restrict__ x,
                                               float* __restrict__ sd) {
    const int b = blockIdx.x;
    const int f = threadIdx.x;
    if (b < GAT_H) {
        const float wf = W[b * GAT_F + f];
        float ps = wf * a[b * 2 * GAT_F + f];
        float pd = wf * a[b * 2 * GAT_F + GAT_F + f];
        #pragma unroll
        for (int off = 32; off > 0; off >>= 1) {
            ps += __shfl_xor(ps, off, 64);
            pd += __shfl_xor(pd, off, 64);
        }
        if (f == 0) { sd[b] = ps; sd[GAT_H + b] = pd; }
    } else {
        float s = 0.0f;
        #pragma unroll
        for (int j = 0; j < GAT_N / 64; ++j) s += x[j * 64 + f];
        #pragma unroll
        for (int off = 32; off > 0; off >>= 1) s += __shfl_xor(s, off, 64);
        if (f == 0) sd[2 * GAT_H] = s * (1.0f / GAT_N);
    }
}

// Table: per (j,h) pair {B,D} = {exp2(L*d_h*x_j), exp2(0.2L*d_h*x_j)},
// stored swapped when d_h<0 so the consumer's compare direction is fixed.
__global__ __launch_bounds__(256) void gat_tab(const float* __restrict__ x,
                                               const float* __restrict__ sd,
                                               float2* __restrict__ tab) {
    const int t  = blockIdx.x * 256 + threadIdx.x;   // 0..49151
    const int h  = t % GAT_H;
    const int jg = t / GAT_H;
    const float d = sd[GAT_H + h];
    const float q = LOG2E * d * x[jg];
    const float B = __builtin_amdgcn_exp2f(q);
    const float D = __builtin_amdgcn_exp2f(0.2f * q);
    tab[t] = (d > 0.0f) ? make_float2(B, D) : make_float2(D, B);
}

// Main: 256 thr = 4 waves/block, 2 rows/wave -> 8 rows/block, 512 blocks.
// Hot body per (j,h,row): cmp, 2x cndmask, mul, 2x fmac -- no transcendentals.
__global__ __launch_bounds__(256) void gat_main(const float* __restrict__ x,
                                                const int* __restrict__ adj,
                                                const float* __restrict__ W,
                                                const float* __restrict__ sd,
                                                const float2* __restrict__ tab,
                                                float* __restrict__ out) {
    __shared__ float  xs[GAT_N];
    __shared__ float2 tileb[TJ * 13];   // 13-pair rows: pad kills b64 conflicts

    const int tid  = threadIdx.x;
    const int lane = tid & 63;
    const int wave = tid >> 6;

    #pragma unroll
    for (int it = 0; it < GAT_N / (256 * 4); ++it)
        ((float4*)xs)[it * 256 + tid] = ((const float4*)x)[it * 256 + tid];

    const int row0 = blockIdx.x * 8 + wave * 2;

    // Per-row constants: A,C (swapped by sign(d_h)) and threshold U = -zi/d_h.
    float Av[2][GAT_H], Cv[2][GAT_H], Uv[2][GAT_H];
    {
        #pragma unroll
        for (int r = 0; r < 2; ++r) {
            const float xi = x[row0 + r];
            #pragma unroll
            for (int h = 0; h < GAT_H; ++h) {
                const float dh = sd[GAT_H + h];
                const float zi = xi * sd[h];
                const float A  = __builtin_amdgcn_exp2f(LOG2E * zi);
                const float C  = __builtin_amdgcn_exp2f(0.2f * LOG2E * zi);
                Uv[r][h] = -zi * __builtin_amdgcn_rcpf(dh);
                const bool dp = dh > 0.0f;
                Av[r][h] = dp ? A : C;
                Cv[r][h] = dp ? C : A;
            }
        }
    }

    float den[2][GAT_H], num[2][GAT_H];
    #pragma unroll
    for (int r = 0; r < 2; ++r)
        #pragma unroll
        for (int h = 0; h < GAT_H; ++h) { den[r][h] = 0.0f; num[r][h] = 0.0f; }

    // Staging map: thread's k-th pair p=k*256+tid -> LDS slot (p/12)*13+(p%12).
    int lidx[12];
    #pragma unroll
    for (int k = 0; k < 12; ++k) {
        const int p = k * 256 + tid;
        lidx[k] = (p / GAT_H) * 13 + (p % GAT_H);
    }

    float2 st[12];
    #pragma unroll
    for (int k = 0; k < 12; ++k) st[k] = tab[k * 256 + tid];

    int acur[2][4], anxt[2][4] = {{0,0,0,0},{0,0,0,0}};
    #pragma unroll
    for (int r = 0; r < 2; ++r)
        #pragma unroll
        for (int e = 0; e < 4; ++e)
            acur[r][e] = adj[(size_t)(row0 + r) * GAT_N + e * 64 + lane];

    __syncthreads();   // xs visible

    for (int T = 0; T < NTILE; ++T) {
        #pragma unroll
        for (int k = 0; k < 12; ++k) tileb[lidx[k]] = st[k];
        __syncthreads();

        if (T < NTILE - 1) {   // prefetch next tile (table + adj) into regs
            const float2* g = tab + (T + 1) * (TJ * GAT_H);
            #pragma unroll
            for (int k = 0; k < 12; ++k) st[k] = g[k * 256 + tid];
            const int jb = (T + 1) * TJ;
            #pragma unroll
            for (int r = 0; r < 2; ++r)
                #pragma unroll
                for (int e = 0; e < 4; ++e)
                    anxt[r][e] = adj[(size_t)(row0 + r) * GAT_N + jb + e * 64 + lane];
        }

        #pragma unroll
        for (int e = 0; e < 4; ++e) {
            const int   jl = e * 64 + lane;
            const float xj = xs[T * TJ + jl];
            float m01[2], xm[2];
            #pragma unroll
            for (int r = 0; r < 2; ++r) {
                const bool mk = acur[r][e] > 0;
                m01[r] = mk ? 1.0f : 0.0f;
                xm[r]  = mk ? xj   : 0.0f;
            }
            const float2* rowp = tileb + jl * 13;
            #pragma unroll
            for (int h = 0; h < GAT_H; ++h) {
                const float2 P = rowp[h];
                #pragma unroll
                for (int r = 0; r < 2; ++r) {
                    const bool  sl = xj > Uv[r][h];
                    const float E  = sl ? P.x : P.y;
                    const float G  = sl ? Av[r][h] : Cv[r][h];
                    const float p  = E * G;
                    den[r][h] = fmaf(p, m01[r], den[r][h]);
                    num[r][h] = fmaf(p, xm[r],  num[r][h]);
                }
            }
        }
        __syncthreads();

        #pragma unroll
        for (int r = 0; r < 2; ++r)
            #pragma unroll
            for (int e = 0; e < 4; ++e)
                acur[r][e] = anxt[r][e];
    }

    const float xmean = sd[2 * GAT_H];
    #pragma unroll
    for (int r = 0; r < 2; ++r) {
        const size_t base = (size_t)(row0 + r) * (GAT_H * GAT_F);
        #pragma unroll
        for (int h = 0; h < GAT_H; ++h) {
            float dn = den[r][h], nm = num[r][h];
            #pragma unroll
            for (int off = 32; off > 0; off >>= 1) {
                dn += __shfl_xor(dn, off, 64);
                nm += __shfl_xor(nm, off, 64);
            }
            const float c = dn > 0.0f ? nm * __builtin_amdgcn_rcpf(dn) : xmean;
            out[base + h * GAT_F + lane] = c * W[h * GAT_F + lane];
        }
    }
}

extern "C" void kernel_launch(void* const* d_in, const int* in_sizes, int n_in,
                              void* d_out, int out_size, void* d_ws, size_t ws_size,
                              hipStream_t stream) {
    const float* x   = (const float*)d_in[0];
    const int*   adj = (const int*)d_in[1];
    const float* W   = (const float*)d_in[2];
    const float* a   = (const float*)d_in[3];
    float* out = (float*)d_out;
    float* sd  = (float*)d_ws;                       // 25 floats
    float2* tab = (float2*)((float*)d_ws + TAB_OFF); // 4096*12 pairs = 384 KB

    gat_prep<<<13, 64, 0, stream>>>(W, a, x, sd);
    gat_tab<<<(GAT_N * GAT_H) / 256, 256, 0, stream>>>(x, sd, tab);
    gat_main<<<GAT_N / 8, 256, 0, stream>>>(x, adj, W, sd, tab, out);
}